// Round 1
// baseline (145.133 us; speedup 1.0000x reference)
//
#include <hip/hip_runtime.h>

#define B_DIM 256
#define T_DIM 8192
#define D_DIM 5
#define NSTEPS 10

static constexpr long long GATE_N = (long long)B_DIM * (2 * T_DIM);   // 4,194,304
static constexpr long long EXT_N  = GATE_N * D_DIM;                   // 20,971,520

// 10-step scan in f64 (matches np f64 ref through the chaotic mod map),
// std/score epilogue in f32 (error ~1e-6, harmless vs threshold).
__device__ __forceinline__ float scan_score(double v0, double v1, double v2, double v3, double v4,
                                            double w0, double w1, double w2, double w3, double w4) {
    float h[NSTEPS];
#pragma unroll
    for (int s = 0; s < NSTEPS; ++s) {
        double res = v0 * w0;
        res = fma(v1, w1, res);
        res = fma(v2, w2, res);
        res = fma(v3, w3, res);
        res = fma(v4, w4, res);
        h[s] = (float)res;
        // np.mod(res, 10.0): result in [0,10), sign of divisor.
        double q = floor(res * 0.1);
        double m = fma(q, -10.0, res);
        m = (m < 0.0)   ? m + 10.0 : m;
        m = (m >= 10.0) ? m - 10.0 : m;
        v4 = v3; v3 = v2; v2 = v1; v1 = v0; v0 = m;
    }
    float mean = 0.f;
#pragma unroll
    for (int s = 0; s < NSTEPS; ++s) mean += h[s];
    mean *= 0.1f;
    float ssd = 0.f;
#pragma unroll
    for (int s = 0; s < NSTEPS; ++s) { float d = h[s] - mean; ssd = fmaf(d, d, ssd); }
    float sd = sqrtf(ssd * (1.0f / 9.0f));   // ddof=1 -> /9
    return 1.0f / (1.0f + sd);
}

__global__ __launch_bounds__(256) void temple_gate_kernel(
    const float* __restrict__ x, const float* __restrict__ temple,
    const float* __restrict__ breath, float* __restrict__ out) {
    __shared__ double sw[10];   // [0..4] = w_main, [5..9] = w_mirror
    __shared__ int s_mode;

    if (threadIdx.x == 0) {
        // seed = mod(mean(x[0,0,:]), 1.0); chaos = R*seed*(1-seed)  (f64, matches np ref)
        double s = 0.0;
        for (int d = 0; d < 5; ++d) s += (double)x[d];
        s = s / 5.0;
        double seed = s - floor(s);
        double chaos = 3.5699456 * seed * (1.0 - seed);
        int mode = (chaos > 0.7) ? 0 : ((chaos > 0.4) ? 1 : 2);
        s_mode = mode;
        // resonance = breath_row . (temple @ vec) = (breath_row @ temple) . vec
        for (int d = 0; d < 5; ++d) {
            double wm = 0.0, wx = 0.0;
            for (int r = 0; r < 4; ++r) {
                double tv = (double)temple[r * 5 + d];
                wm += (double)breath[r] * tv;       // breath_main = breath[0:4]
                wx += (double)breath[r + 1] * tv;   // breath_mirror = breath[1:5]
            }
            sw[d] = wm; sw[5 + d] = wx;
        }
        if (blockIdx.x == 0) out[GATE_N + EXT_N] = (float)mode;   // mode_code (f32 slot)
    }
    __syncthreads();

    const int mode = s_mode;
    const double wm0 = sw[0], wm1 = sw[1], wm2 = sw[2], wm3 = sw[3], wm4 = sw[4];
    const double wx0 = sw[5], wx1 = sw[6], wx2 = sw[7], wx3 = sw[8], wx4 = sw[9];

    const long long tid = (long long)blockIdx.x * blockDim.x + threadIdx.x;  // [0, B*T)
    const int b = (int)(tid >> 13);          // /8192
    const int t = (int)(tid & (T_DIM - 1));

    const float* xp = x + ((long long)b * T_DIM + t) * D_DIM;
    const float x0 = xp[0], x1 = xp[1], x2 = xp[2], x3 = xp[3], x4 = xp[4];

    float* gate = out;
    float* ext  = out + GATE_N;
    const long long rowBase = (long long)b * (2 * T_DIM);

    // ---- main half: extended[b, t] = x[b, t]; breath_main scan
    {
        const long long o = (rowBase + t) * D_DIM;
        ext[o + 0] = x0; ext[o + 1] = x1; ext[o + 2] = x2; ext[o + 3] = x3; ext[o + 4] = x4;
        gate[rowBase + t] = scan_score((double)x0, (double)x1, (double)x2, (double)x3, (double)x4,
                                       wm0, wm1, wm2, wm3, wm4);
    }

    // ---- mirror half: mode 0 -> 9-x at T+t; mode 1 -> x at T+(T-1-t); mode 2 -> x at T+t
    {
        double m0 = (double)x0, m1 = (double)x1, m2 = (double)x2, m3 = (double)x3, m4 = (double)x4;
        float  f0 = x0, f1 = x1, f2 = x2, f3 = x3, f4 = x4;
        if (mode == 0) {
            m0 = 9.0 - m0; m1 = 9.0 - m1; m2 = 9.0 - m2; m3 = 9.0 - m3; m4 = 9.0 - m4;
            f0 = 9.f - x0; f1 = 9.f - x1; f2 = 9.f - x2; f3 = 9.f - x3; f4 = 9.f - x4;
        }
        const int tm = (mode == 1) ? (T_DIM - 1 - t) : t;
        const long long p = rowBase + T_DIM + tm;
        const long long o = p * D_DIM;
        ext[o + 0] = f0; ext[o + 1] = f1; ext[o + 2] = f2; ext[o + 3] = f3; ext[o + 4] = f4;
        gate[p] = scan_score(m0, m1, m2, m3, m4, wx0, wx1, wx2, wx3, wx4);
    }
}

extern "C" void kernel_launch(void* const* d_in, const int* in_sizes, int n_in,
                              void* d_out, int out_size, void* d_ws, size_t ws_size,
                              hipStream_t stream) {
    const float* x      = (const float*)d_in[0];   // (256, 8192, 5) f32
    const float* temple = (const float*)d_in[1];   // (4, 5) f32
    const float* breath = (const float*)d_in[2];   // (5,) f32
    float* out = (float*)d_out;                    // [gate | extended_x | mode_code]

    const int total = B_DIM * T_DIM;               // one thread per (b, t)
    temple_gate_kernel<<<total / 256, 256, 0, stream>>>(x, temple, breath, out);
}